// Round 10
// baseline (98.123 us; speedup 1.0000x reference)
//
#include <hip/hip_runtime.h>

// N-body all-pairs, N=8192, fp32 — ROUND-10 DIAGNOSTIC (2x work on purpose).
//
// r4-r9: six structurally different kernels all land at ~28-31us inferred,
// but the kernel has been INVISIBLE below the 40us harness poison fills
// since r4 -> no counters, blind config-shuffling. This round doubles the
// j-loop (forward pass -> acc A, reverse pass -> acc B, output 0.5*(A+B);
// reverse order defeats cross-loop CSE) so the kernel surfaces at ~2x
// plateau with full counters. Forces identical to single pass.
//
// Read-out: VALUBusy>=85% -> issue-bound, count insts & diet.
//           VALUBusy~50% + occupancy ok -> in-wave latency, go disasm-level.
//           occupancy<15% -> resident-wave problem.

typedef float v2f __attribute__((ext_vector_type(2)));

constexpr int   NBODY   = 8192;
constexpr int   BLOCK   = 256;
constexpr int   IBLK    = 4;                   // bodies/thread = 2 pk groups
constexpr int   GRP     = IBLK / 2;
constexpr int   IBODIES = BLOCK * IBLK;        // 1024
constexpr int   JSPLIT  = 128;
constexpr int   JPER    = NBODY / JSPLIT;      // 64
constexpr float SOFT2   = 0.01f * 0.01f;
constexpr int   OUTE    = NBODY * 3;

__global__ __launch_bounds__(BLOCK, 4) void nbody_forces_2x(
    const float* __restrict__ pos,
    const float* __restrict__ mass,
    float*       __restrict__ part)
{
    const int tid   = threadIdx.x;
    const int iBase = blockIdx.x * IBODIES + tid;
    const int j0    = blockIdx.y * JPER;

    __shared__ float4 sh[JPER];
    if (tid < JPER) {
        const int j = j0 + tid;
        sh[tid] = make_float4(pos[3 * j + 0], pos[3 * j + 1], pos[3 * j + 2], mass[j]);
    }

    v2f px[GRP], py[GRP], pz[GRP];
    #pragma unroll
    for (int g = 0; g < GRP; ++g) {
        const int i0 = iBase + (2 * g + 0) * BLOCK;
        const int i1 = iBase + (2 * g + 1) * BLOCK;
        px[g] = (v2f){pos[3 * i0 + 0], pos[3 * i1 + 0]};
        py[g] = (v2f){pos[3 * i0 + 1], pos[3 * i1 + 1]};
        pz[g] = (v2f){pos[3 * i0 + 2], pos[3 * i1 + 2]};
    }
    __syncthreads();

    const v2f soft2 = (v2f){SOFT2, SOFT2};

    v2f fx1[GRP], fy1[GRP], fz1[GRP], fx2[GRP], fy2[GRP], fz2[GRP];
    #pragma unroll
    for (int g = 0; g < GRP; ++g) {
        fx1[g] = (v2f)0.f; fy1[g] = (v2f)0.f; fz1[g] = (v2f)0.f;
        fx2[g] = (v2f)0.f; fy2[g] = (v2f)0.f; fz2[g] = (v2f)0.f;
    }

    // ---- pass 1: forward k ----
    #pragma unroll 4
    for (int k = 0; k < JPER; ++k) {
        const float4 p = sh[k];
        const v2f jx = (v2f){p.x, p.x}, jy = (v2f){p.y, p.y};
        const v2f jz = (v2f){p.z, p.z}, jm = (v2f){p.w, p.w};
        #pragma unroll
        for (int g = 0; g < GRP; ++g) {
            const v2f dx = jx - px[g], dy = jy - py[g], dz = jz - pz[g];
            v2f d2 = __builtin_elementwise_fma(dz, dz, soft2);
            d2     = __builtin_elementwise_fma(dy, dy, d2);
            d2     = __builtin_elementwise_fma(dx, dx, d2);
            v2f inv;
            inv.x = __builtin_amdgcn_rsqf(d2.x);
            inv.y = __builtin_amdgcn_rsqf(d2.y);
            const v2f s = inv * inv * inv * jm;
            fx1[g] = __builtin_elementwise_fma(s, dx, fx1[g]);
            fy1[g] = __builtin_elementwise_fma(s, dy, fy1[g]);
            fz1[g] = __builtin_elementwise_fma(s, dz, fz1[g]);
        }
    }

    // ---- pass 2: reverse k (defeats cross-loop CSE; same value set) ----
    #pragma unroll 4
    for (int k = JPER - 1; k >= 0; --k) {
        const float4 p = sh[k];
        const v2f jx = (v2f){p.x, p.x}, jy = (v2f){p.y, p.y};
        const v2f jz = (v2f){p.z, p.z}, jm = (v2f){p.w, p.w};
        #pragma unroll
        for (int g = 0; g < GRP; ++g) {
            const v2f dx = jx - px[g], dy = jy - py[g], dz = jz - pz[g];
            v2f d2 = __builtin_elementwise_fma(dz, dz, soft2);
            d2     = __builtin_elementwise_fma(dy, dy, d2);
            d2     = __builtin_elementwise_fma(dx, dx, d2);
            v2f inv;
            inv.x = __builtin_amdgcn_rsqf(d2.x);
            inv.y = __builtin_amdgcn_rsqf(d2.y);
            const v2f s = inv * inv * inv * jm;
            fx2[g] = __builtin_elementwise_fma(s, dx, fx2[g]);
            fy2[g] = __builtin_elementwise_fma(s, dy, fy2[g]);
            fz2[g] = __builtin_elementwise_fma(s, dz, fz2[g]);
        }
    }

    float* dst = part + (size_t)blockIdx.y * OUTE;
    #pragma unroll
    for (int g = 0; g < GRP; ++g) {
        #pragma unroll
        for (int h = 0; h < 2; ++h) {
            const int i = iBase + (2 * g + h) * BLOCK;
            dst[3 * i + 0] = 0.5f * (fx1[g][h] + fx2[g][h]);
            dst[3 * i + 1] = 0.5f * (fy1[g][h] + fy2[g][h]);
            dst[3 * i + 2] = 0.5f * (fz1[g][h] + fz2[g][h]);
        }
    }
}

__global__ __launch_bounds__(256) void reduce_kernel(
    const float* __restrict__ part,
    float*       __restrict__ out)
{
    const int e = blockIdx.x * blockDim.x + threadIdx.x;
    float s = 0.f;
    #pragma unroll 8
    for (int k = 0; k < JSPLIT; ++k)
        s += part[(size_t)k * OUTE + e];
    out[e] = s;
}

extern "C" void kernel_launch(void* const* d_in, const int* in_sizes, int n_in,
                              void* d_out, int out_size, void* d_ws, size_t ws_size,
                              hipStream_t stream) {
    const float* pos  = (const float*)d_in[0];
    const float* mass = (const float*)d_in[1];
    float* out = (float*)d_out;

    float* part = (float*)d_ws;          // [JSPLIT][OUTE] = 12.6 MB

    dim3 grid(NBODY / IBODIES, JSPLIT);  // (8, 128) = 1024 blocks
    nbody_forces_2x<<<grid, BLOCK, 0, stream>>>(pos, mass, part);

    reduce_kernel<<<OUTE / 256, 256, 0, stream>>>(part, out);
}

// Round 11
// 84.835 us; speedup vs baseline: 1.1566x; 1.1566x over previous
//
#include <hip/hip_runtime.h>

// N-body all-pairs gravitational force, N=8192, fp32.
//
// Round-11: r10 diagnostic (2x-work kernel, full counters) showed:
//   VALUBusy 63%, Occupancy 23% (7.4 of 32 waves/CU), issue time == model
//   (13.7us/pass). => stall-bound from too few resident waves, NOT issue.
//   Also: v_pk_*_f32 is half-rate per element (157TF = scalar rate), so
//   r8/r9 pk-packing was issue-neutral. Back to scalar.
// Fix: IBLK=2 (VGPR ~40 -> 8 waves/SIMD allowed; keeps shared LDS pipe
//   at ~70% capacity: 1 ds_read_b128 per ~17.5 CU-cyc vs 1/12 limit),
//   JSPLIT=128 -> 2048 blocks = 8 blocks/CU = 32 waves/CU resident.
// Epilogue: plain partial stores [128][N*3] + reduce (r5: atomics thrash).
// Issue floor ~14us; predicting ~15-16us realized, VALUBusy >= 80%.

constexpr int   NBODY   = 8192;
constexpr int   BLOCK   = 256;
constexpr int   IBLK    = 2;
constexpr int   IBODIES = BLOCK * IBLK;        // 512 i's per block
constexpr int   JSPLIT  = 128;
constexpr int   JPER    = NBODY / JSPLIT;      // 64 j's per block
constexpr float SOFT2   = 0.01f * 0.01f;
constexpr int   OUTE    = NBODY * 3;           // 24576

__global__ __launch_bounds__(BLOCK, 8) void nbody_forces(
    const float* __restrict__ pos,       // [N,3]
    const float* __restrict__ mass,      // [N]
    float*       __restrict__ part)      // [JSPLIT][N*3] partials
{
    const int tid   = threadIdx.x;
    const int iBase = blockIdx.x * IBODIES + tid;
    const int j0    = blockIdx.y * JPER;

    __shared__ float4 sh[JPER];
    if (tid < JPER) {
        const int j = j0 + tid;
        sh[tid] = make_float4(pos[3 * j + 0], pos[3 * j + 1], pos[3 * j + 2], mass[j]);
    }

    float px[IBLK], py[IBLK], pz[IBLK];
    #pragma unroll
    for (int b = 0; b < IBLK; ++b) {
        const int i = iBase + b * BLOCK;
        px[b] = pos[3 * i + 0];
        py[b] = pos[3 * i + 1];
        pz[b] = pos[3 * i + 2];
    }
    __syncthreads();

    float fx[IBLK], fy[IBLK], fz[IBLK];
    #pragma unroll
    for (int b = 0; b < IBLK; ++b) { fx[b] = 0.f; fy[b] = 0.f; fz[b] = 0.f; }

    #pragma unroll 4
    for (int k = 0; k < JPER; ++k) {
        const float4 p = sh[k];            // uniform addr -> HW broadcast
        #pragma unroll
        for (int b = 0; b < IBLK; ++b) {   // 2 independent chains
            const float dx = p.x - px[b];
            const float dy = p.y - py[b];
            const float dz = p.z - pz[b];
            const float d2 = fmaf(dx, dx, fmaf(dy, dy, fmaf(dz, dz, SOFT2)));
            const float inv = __builtin_amdgcn_rsqf(d2);    // v_rsq_f32
            const float s   = p.w * inv * inv * inv;        // G = 1
            fx[b] = fmaf(s, dx, fx[b]);
            fy[b] = fmaf(s, dy, fy[b]);
            fz[b] = fmaf(s, dz, fz[b]);
            // j == i: diff = 0 -> contribution 0, matches reference.
        }
    }

    float* dst = part + (size_t)blockIdx.y * OUTE;
    #pragma unroll
    for (int b = 0; b < IBLK; ++b) {
        const int i = iBase + b * BLOCK;
        dst[3 * i + 0] = fx[b];
        dst[3 * i + 1] = fy[b];
        dst[3 * i + 2] = fz[b];
    }
}

__global__ __launch_bounds__(256) void reduce_kernel(
    const float* __restrict__ part,      // [JSPLIT][OUTE]
    float*       __restrict__ out)       // [OUTE]
{
    const int e = blockIdx.x * blockDim.x + threadIdx.x;   // 0..OUTE-1
    float s = 0.f;
    #pragma unroll 8
    for (int k = 0; k < JSPLIT; ++k)
        s += part[(size_t)k * OUTE + e];
    out[e] = s;
}

extern "C" void kernel_launch(void* const* d_in, const int* in_sizes, int n_in,
                              void* d_out, int out_size, void* d_ws, size_t ws_size,
                              hipStream_t stream) {
    const float* pos  = (const float*)d_in[0];
    const float* mass = (const float*)d_in[1];
    float* out = (float*)d_out;

    float* part = (float*)d_ws;          // [JSPLIT][OUTE] = 12.6 MB

    dim3 grid(NBODY / IBODIES, JSPLIT);  // (16, 128) = 2048 blocks
    nbody_forces<<<grid, BLOCK, 0, stream>>>(pos, mass, part);

    reduce_kernel<<<OUTE / 256, 256, 0, stream>>>(part, out);
}

// Round 12
// 82.477 us; speedup vs baseline: 1.1897x; 1.0286x over previous
//
#include <hip/hip_runtime.h>

// N-body all-pairs gravitational force, N=8192, fp32.
//
// Round-12: single-pass version of the ONLY counter-measured kernel (r10
// diagnostic: 2x-work variant ran 43.4us, VALUBusy 63%, 0 conflicts ->
// single pass ~21.7us, the best known core). r11 (scalar, IBLK=2, 2048
// blocks) inferred ~29us => the pk-GRP2/IBLK=4/1024-block structure wins;
// shipping it verbatim minus the duplicate pass. VALUBusy 63% matches the
// issue model exactly (rsq=8cyc counted); remaining 37% stall has resisted
// TLP/ILP/stage-major/prefetch levers across r4-r11.

typedef float v2f __attribute__((ext_vector_type(2)));

constexpr int   NBODY   = 8192;
constexpr int   BLOCK   = 256;
constexpr int   IBLK    = 4;                   // bodies/thread = 2 pk groups
constexpr int   GRP     = IBLK / 2;
constexpr int   IBODIES = BLOCK * IBLK;        // 1024
constexpr int   JSPLIT  = 128;
constexpr int   JPER    = NBODY / JSPLIT;      // 64
constexpr float SOFT2   = 0.01f * 0.01f;
constexpr int   OUTE    = NBODY * 3;

__global__ __launch_bounds__(BLOCK, 4) void nbody_forces(
    const float* __restrict__ pos,
    const float* __restrict__ mass,
    float*       __restrict__ part)
{
    const int tid   = threadIdx.x;
    const int iBase = blockIdx.x * IBODIES + tid;
    const int j0    = blockIdx.y * JPER;

    __shared__ float4 sh[JPER];
    if (tid < JPER) {
        const int j = j0 + tid;
        sh[tid] = make_float4(pos[3 * j + 0], pos[3 * j + 1], pos[3 * j + 2], mass[j]);
    }

    v2f px[GRP], py[GRP], pz[GRP];
    #pragma unroll
    for (int g = 0; g < GRP; ++g) {
        const int i0 = iBase + (2 * g + 0) * BLOCK;
        const int i1 = iBase + (2 * g + 1) * BLOCK;
        px[g] = (v2f){pos[3 * i0 + 0], pos[3 * i1 + 0]};
        py[g] = (v2f){pos[3 * i0 + 1], pos[3 * i1 + 1]};
        pz[g] = (v2f){pos[3 * i0 + 2], pos[3 * i1 + 2]};
    }
    __syncthreads();

    const v2f soft2 = (v2f){SOFT2, SOFT2};

    v2f fx[GRP], fy[GRP], fz[GRP];
    #pragma unroll
    for (int g = 0; g < GRP; ++g) {
        fx[g] = (v2f)0.f; fy[g] = (v2f)0.f; fz[g] = (v2f)0.f;
    }

    #pragma unroll 4
    for (int k = 0; k < JPER; ++k) {
        const float4 p = sh[k];
        const v2f jx = (v2f){p.x, p.x}, jy = (v2f){p.y, p.y};
        const v2f jz = (v2f){p.z, p.z}, jm = (v2f){p.w, p.w};
        #pragma unroll
        for (int g = 0; g < GRP; ++g) {
            const v2f dx = jx - px[g], dy = jy - py[g], dz = jz - pz[g];
            v2f d2 = __builtin_elementwise_fma(dz, dz, soft2);
            d2     = __builtin_elementwise_fma(dy, dy, d2);
            d2     = __builtin_elementwise_fma(dx, dx, d2);
            v2f inv;
            inv.x = __builtin_amdgcn_rsqf(d2.x);
            inv.y = __builtin_amdgcn_rsqf(d2.y);
            const v2f s = inv * inv * inv * jm;
            fx[g] = __builtin_elementwise_fma(s, dx, fx[g]);
            fy[g] = __builtin_elementwise_fma(s, dy, fy[g]);
            fz[g] = __builtin_elementwise_fma(s, dz, fz[g]);
            // j == i: diff = 0 -> contribution 0, matches reference.
        }
    }

    float* dst = part + (size_t)blockIdx.y * OUTE;
    #pragma unroll
    for (int g = 0; g < GRP; ++g) {
        #pragma unroll
        for (int h = 0; h < 2; ++h) {
            const int i = iBase + (2 * g + h) * BLOCK;
            dst[3 * i + 0] = fx[g][h];
            dst[3 * i + 1] = fy[g][h];
            dst[3 * i + 2] = fz[g][h];
        }
    }
}

__global__ __launch_bounds__(256) void reduce_kernel(
    const float* __restrict__ part,
    float*       __restrict__ out)
{
    const int e = blockIdx.x * blockDim.x + threadIdx.x;
    float s = 0.f;
    #pragma unroll 8
    for (int k = 0; k < JSPLIT; ++k)
        s += part[(size_t)k * OUTE + e];
    out[e] = s;
}

extern "C" void kernel_launch(void* const* d_in, const int* in_sizes, int n_in,
                              void* d_out, int out_size, void* d_ws, size_t ws_size,
                              hipStream_t stream) {
    const float* pos  = (const float*)d_in[0];
    const float* mass = (const float*)d_in[1];
    float* out = (float*)d_out;

    float* part = (float*)d_ws;          // [JSPLIT][OUTE] = 12.6 MB

    dim3 grid(NBODY / IBODIES, JSPLIT);  // (8, 128) = 1024 blocks
    nbody_forces<<<grid, BLOCK, 0, stream>>>(pos, mass, part);

    reduce_kernel<<<OUTE / 256, 256, 0, stream>>>(part, out);
}